// Round 12
// baseline (258.928 us; speedup 1.0000x reference)
//
#include <hip/hip_runtime.h>

#define H    128
#define WP   130
#define BPF  516           // border pixels per face image
#define TBLN 3096          // 6 * 516
#define NIMG 6144

// Face order: back(0), down(1), front(2), left(3), right(4), top(5)
__constant__ int c_R[6][9] = {
  {-1,0,0,  0,1,0,  0,0,-1},
  { 1,0,0,  0,0,-1, 0,1,0 },
  { 1,0,0,  0,1,0,  0,0,1 },
  { 0,0,1,  0,1,0, -1,0,0 },
  { 0,0,-1, 0,1,0,  1,0,0 },
  { 1,0,0,  0,0,1,  0,-1,0},
};
// NEIGHBORS[face][side], side order: up(0), down(1), left(2), right(3)
__constant__ int c_conn[6][4] = {
  {5,1,4,3}, {2,0,3,4}, {5,1,3,4}, {5,1,0,2}, {5,1,2,0}, {0,2,3,4},
};

#define INV_FP (65.0f / 4128.0f)

// ---------- kernel A: build border table (3096 entries) ------------------
__global__ void __launch_bounds__(256)
border_table_kernel(int* __restrict__ tb_face, int4* __restrict__ tb_idx,
                    float4* __restrict__ tb_w) {
  int t = blockIdx.x * 256 + threadIdx.x;
  if (t >= TBLN) return;
  int face = t / BPF;
  int k    = t - face * BPF;

  int r, c;
  if (k < 130)      { r = 0;        c = k; }
  else if (k < 260) { r = WP - 1;   c = k - 130; }
  else if (k < 388) { r = k - 259;  c = 0; }
  else              { r = k - 387;  c = WP - 1; }

  int fs = -1;
  int4  idx = make_int4(0, 0, 0, 0);
  float4 w  = make_float4(0.f, 0.f, 0.f, 0.f);

  int cand[2]; int nc = 0;
  if (c == WP - 1) cand[nc++] = 3;
  if (c == 0)      cand[nc++] = 2;
  if (r == WP - 1) cand[nc++] = 1;
  if (r == 0)      cand[nc++] = 0;

  float uc = ((float)c - 64.5f) * INV_FP;
  float ur = ((float)r - 64.5f) * INV_FP;

  for (int kk = 0; kk < nc; ++kk) {
    int s  = cand[kk];
    int cf = c_conn[face][s];
    const int* Rc = c_R[cf];
    const int* Rf = c_R[face];
    float g[3];
    #pragma unroll
    for (int i = 0; i < 3; ++i) {
      float acc = 0.0f;
      #pragma unroll
      for (int j = 0; j < 3; ++j) {
        int rr = Rc[i*3+0]*Rf[j*3+0] + Rc[i*3+1]*Rf[j*3+1] + Rc[i*3+2]*Rf[j*3+2];
        float dj = (j == 0) ? uc : (j == 1) ? ur : 1.0f;
        acc += (float)rr * dj;
      }
      g[i] = acc;
    }
    float x = g[0] / g[2];
    float y = g[1] / g[2];
    if (fabsf(x) <= 1.01f && fabsf(y) <= 1.01f) {
      x = fminf(fmaxf(x, -1.0f), 1.0f);
      y = fminf(fmaxf(y, -1.0f), 1.0f);
      float xp = (x + 1.0f) * 0.5f * (float)(H - 1);
      float yp = (y + 1.0f) * 0.5f * (float)(H - 1);
      float x0 = floorf(xp), y0 = floorf(yp);
      float wx = xp - x0,    wy = yp - y0;
      int x0i = min(max((int)x0, 0), H - 1);
      int x1i = min(x0i + 1, H - 1);
      int y0i = min(max((int)y0, 0), H - 1);
      int y1i = min(y0i + 1, H - 1);
      fs  = cf;
      idx = make_int4(y0i * H + x0i, y0i * H + x1i, y1i * H + x0i, y1i * H + x1i);
      w   = make_float4((1.f - wx) * (1.f - wy), wx * (1.f - wy),
                        (1.f - wx) * wy,         wx * wy);
      break;
    }
  }
  tb_face[t] = fs;
  tb_idx[t]  = idx;
  tb_w[t]    = w;
}

// ---------- kernel B: XCD-grouped fused bulk + edge ----------------------
// Linear grid of 12288 blocks. Bijective remap wgid=(b%8)*1536+b/8 puts
// CONSECUTIVE wgid on the SAME XCD (HW round-robins consecutive blockIdx
// across the 8 XCDs). wgid = g*2 + role; g enumerates (rep,ch) x face so
// all 12 blocks (6 faces x {bulk,edge}) of one (rep,ch) group run adjacent
// on one XCD -> edge gathers hit local L2, bulk/edge shared output lines
// stay in one L2. Bulk/edge bodies are R11-verified, byte-identical logic.
__global__ void __launch_bounds__(1024)
swz_kernel(const float* __restrict__ in, float4* __restrict__ out4,
           const int* __restrict__ tb_face,
           const int4* __restrict__ tb_idx,
           const float4* __restrict__ tb_w) {
  const unsigned b    = blockIdx.x;                 // 0..12287
  const unsigned wgid = (b & 7u) * 1536u + (b >> 3);
  const unsigned g    = wgid >> 1;                  // 0..6143
  const unsigned role = wgid & 1u;

  const unsigned rc   = g / 6u;                     // (rep,ch) group 0..1023
  const unsigned face = g - rc * 6u;
  const unsigned rep  = rc >> 8;
  const unsigned ch   = rc & 255u;
  const unsigned img  = ((rep * 6u + face) << 8) + ch;

  if (role == 0u) {
    // ---- bulk: 3968 clean quads, 4 tasks/thread, 8-deep MLP ----
    const unsigned u = threadIdx.x;
    const float4* bin = (const float4*)in + ((size_t)img << 12);

    float4 A[4], B[4];
    unsigned oq[4], od[4];
    bool act[4];
    #pragma unroll
    for (int k = 0; k < 4; ++k) {
      unsigned tau = u + ((unsigned)k << 10);
      act[k] = (tau < 3968u);
      unsigned tt = act[k] ? tau : 0u;
      unsigned j  = tt / 62u;                      // magic-mul
      unsigned i  = tt - j * 62u;
      unsigned m  = (j == 0u && i < 31u) ? 64u : j;
      unsigned o  = (i >= 31u) ? 1u : 0u;
      unsigned q  = i + 1u + o;
      unsigned ib = (m << 6) + q - 33u;
      A[k] = bin[ib];
      B[k] = bin[ib + 1u];
      oq[k] = m * 65u + q;
      od[k] = o;
    }
    const size_t ob = (size_t)img * 4225u;
    #pragma unroll
    for (int k = 0; k < 4; ++k) {
      if (!act[k]) continue;                       // wave-uniform (896=14*64)
      float4 o = od[k] ? make_float4(A[k].y, A[k].z, A[k].w, B[k].x)
                       : make_float4(A[k].w, B[k].x, B[k].y, B[k].z);
      out4[ob + oq[k]] = o;
    }
  } else {
    // ---- edge: 257 quads for this image (R7/R11-verified table path) ----
    const unsigned k = threadIdx.x;
    if (k >= 257u) return;

    unsigned qk;
    if (k < 33u)       qk = k;                     // pair 0: q 0..32
    else if (k == 33u) qk = 64u;                   // pair 0: q 64
    else if (k == 34u) qk = 4160u;                 // pair 64: q 0
    else if (k < 68u)  qk = 4192u + (k - 35u);     // pair 64: q 32..64
    else {
      unsigned jj = k - 68u;                       // 0..188
      unsigned mm = 1u + jj / 3u;                  // 1..63
      unsigned w  = jj - 3u * (jj / 3u);           // 0,1,2
      qk = 65u * mm + ((w == 0u) ? 0u : (w == 1u) ? 32u : 64u);
    }

    unsigned p = qk << 2;
    unsigned r = p / 130u;
    unsigned c = p - r * 130u;
    float vals[4];
    #pragma unroll
    for (int e = 0; e < 4; ++e) {
      float v;
      if ((r - 1u) < 128u && (c - 1u) < 128u) {
        v = in[((size_t)img << 14) + ((r - 1u) << 7) + (c - 1u)];
      } else {
        unsigned tk = (r == 0u)   ? c
                    : (r == 129u) ? (130u + c)
                    : (c == 0u)   ? (259u + r)
                    :               (387u + r);
        unsigned ti = face * (unsigned)BPF + tk;
        int fs = tb_face[ti];
        v = 0.0f;
        if (fs >= 0) {
          int4   id = tb_idx[ti];
          float4 w  = tb_w[ti];
          const float* s = in +
              ((size_t)(((rep * 6u + (unsigned)fs) << 8) + ch) << 14);
          v = w.x * s[id.x] + w.y * s[id.y] + w.z * s[id.z] + w.w * s[id.w];
        }
      }
      vals[e] = v;
      if (++c == 130u) { c = 0u; ++r; }
    }
    out4[(size_t)img * 4225u + qk] =
        make_float4(vals[0], vals[1], vals[2], vals[3]);
  }
}

// ---------- fallback: round-2 simple kernels ------------------------------
__global__ void __launch_bounds__(256)
interior_kernel(const float4* __restrict__ in4, float* __restrict__ out) {
  unsigned t = blockIdx.x * 256u + threadIdx.x;
  unsigned c4  = t & 31u;
  unsigned r   = (t >> 5) & 127u;
  unsigned img = t >> 12;
  float4 v = in4[t];
  unsigned o = img * 16900u + (r + 1u) * 130u + 1u + (c4 << 2);
  out[o] = v.x; out[o + 1] = v.y; out[o + 2] = v.z; out[o + 3] = v.w;
}

__global__ void __launch_bounds__(256)
border_kernel(const float* __restrict__ in, float* __restrict__ out) {
  unsigned tid = blockIdx.x * 256u + threadIdx.x;
  const unsigned total = 6144u * 516u;
  if (tid >= total) return;
  unsigned img = tid / 516u;
  unsigned k   = tid - img * 516u;
  int r, c;
  if (k < 130u)      { r = 0;               c = (int)k; }
  else if (k < 260u) { r = WP - 1;          c = (int)(k - 130u); }
  else if (k < 388u) { r = (int)(k - 259u); c = 0; }
  else               { r = (int)(k - 387u); c = WP - 1; }
  int n = (int)(img >> 8), ch = (int)(img & 255u);
  int face = n % 6, rep = n / 6;
  float v = 0.0f;
  int cand[2]; int nc = 0;
  if (c == WP - 1) cand[nc++] = 3;
  if (c == 0)      cand[nc++] = 2;
  if (r == WP - 1) cand[nc++] = 1;
  if (r == 0)      cand[nc++] = 0;
  float uc = ((float)c - 64.5f) * INV_FP;
  float ur = ((float)r - 64.5f) * INV_FP;
  for (int kk = 0; kk < nc; ++kk) {
    int s = cand[kk], cf = c_conn[face][s];
    const int* Rc = c_R[cf]; const int* Rf = c_R[face];
    float g[3];
    #pragma unroll
    for (int i = 0; i < 3; ++i) {
      float acc = 0.0f;
      #pragma unroll
      for (int j = 0; j < 3; ++j) {
        int rr = Rc[i*3+0]*Rf[j*3+0] + Rc[i*3+1]*Rf[j*3+1] + Rc[i*3+2]*Rf[j*3+2];
        float dj = (j == 0) ? uc : (j == 1) ? ur : 1.0f;
        acc += (float)rr * dj;
      }
      g[i] = acc;
    }
    float x = g[0] / g[2], y = g[1] / g[2];
    if (fabsf(x) <= 1.01f && fabsf(y) <= 1.01f) {
      x = fminf(fmaxf(x, -1.0f), 1.0f);
      y = fminf(fmaxf(y, -1.0f), 1.0f);
      const float* src = in + ((size_t)((rep * 6 + cf) * 256 + ch)) * H * H;
      float xp = (x + 1.0f) * 0.5f * (float)(H - 1);
      float yp = (y + 1.0f) * 0.5f * (float)(H - 1);
      float x0 = floorf(xp), y0 = floorf(yp);
      float wx = xp - x0, wy = yp - y0;
      int x0i = min(max((int)x0, 0), H - 1);
      int x1i = min(x0i + 1, H - 1);
      int y0i = min(max((int)y0, 0), H - 1);
      int y1i = min(y0i + 1, H - 1);
      v = src[y0i*H+x0i]*(1.f-wx)*(1.f-wy) + src[y0i*H+x1i]*wx*(1.f-wy)
        + src[y1i*H+x0i]*(1.f-wx)*wy       + src[y1i*H+x1i]*wx*wy;
      break;
    }
  }
  out[(unsigned)img * 16900u + (unsigned)r * 130u + (unsigned)c] = v;
}

extern "C" void kernel_launch(void* const* d_in, const int* in_sizes, int n_in,
                              void* d_out, int out_size, void* d_ws, size_t ws_size,
                              hipStream_t stream) {
  (void)in_sizes; (void)n_in; (void)out_size;
  const float* in = (const float*)d_in[0];
  float* out = (float*)d_out;

  const size_t tbl_bytes = (size_t)TBLN * (4 + 16 + 16);   // 111,456 B

  if (d_ws != nullptr && ws_size >= tbl_bytes) {
    int*    tb_face = (int*)d_ws;
    int4*   tb_idx  = (int4*)(tb_face + TBLN);
    float4* tb_w    = (float4*)(tb_idx + TBLN);
    border_table_kernel<<<(TBLN + 255) / 256, 256, 0, stream>>>(
        tb_face, tb_idx, tb_w);

    swz_kernel<<<12288, 1024, 0, stream>>>(in, (float4*)out,
                                           tb_face, tb_idx, tb_w);
  } else {
    interior_kernel<<<98304, 256, 0, stream>>>((const float4*)in, out);
    const unsigned btotal = 6144u * 516u;
    border_kernel<<<(btotal + 255u) / 256u, 256, 0, stream>>>(in, out);
  }
}